// Round 6
// baseline (51.864 us; speedup 1.0000x reference)
//
#include <hip/hip_runtime.h>
#include <hip/hip_fp16.h>
#include <hip/hip_fp8.h>
#include <stdint.h>

#define VOCAB 40000
#define NW    100
#define N1    100
#define N2    100
#define BB    4096
#define LL    343
#define PP    86      // pooling length: (343-1)/4 + 1
#define SROWB 128     // S row stride in BYTES (one 128-B cache line, fp8)

typedef _Float16 v8h __attribute__((ext_vector_type(8)));
typedef float    v4f __attribute__((ext_vector_type(4)));
typedef float    v2f __attribute__((ext_vector_type(2)));

union H8 { v8h v; _Float16 e[8]; };

__device__ __forceinline__ unsigned char enc_fp8(float v) {
#if __has_builtin(__builtin_amdgcn_cvt_pk_fp8_f32)
    int pk = __builtin_amdgcn_cvt_pk_fp8_f32(v, v, 0, false);
    return (unsigned char)(pk & 0xff);
#else
    __hip_fp8_e4m3 h(v);
    return h.__x;
#endif
}

__device__ __forceinline__ v2f dec2_fp8(unsigned int us) {
#if __has_builtin(__builtin_amdgcn_cvt_pk_f32_fp8)
    return __builtin_amdgcn_cvt_pk_f32_fp8((int)us, false);
#else
    __hip_fp8_e4m3 a, b;
    a.__x = (unsigned char)(us & 0xff);
    b.__x = (unsigned char)((us >> 8) & 0xff);
    v2f r; r.x = (float)a; r.y = (float)b; return r;
#endif
}

// ---------------------------------------------------------------------------
// k_table: S[v][f] = sum_k wv[v][k]*(W1[f][k]+W1[f][100+k]) via
// mfma_f32_16x16x32_f16, output fp8 e4m3 rows of 128 B. 64 vocab rows/block,
// 4 waves, 7 col-tiles x 4 k-steps. LDS XOR-swizzled for ds_read_b128.
// ---------------------------------------------------------------------------
__global__ __launch_bounds__(256) void k_table(const float* __restrict__ word_vec,
                                               const float* __restrict__ W1,
                                               unsigned char* __restrict__ S8) {
    const int tid = threadIdx.x;
    __shared__ _Float16 wt[64 * 128];    // word tile, swizzled   (16 KB)
    __shared__ _Float16 eff[112 * 128];  // eff filters, swizzled (28 KB)
    const int vbase = blockIdx.x * 64;

    // ---- stage word tile: 64 rows x 16 chunks of 8 halfs ----
    for (int c = tid; c < 64 * 16; c += 256) {
        const int r = c >> 4, cc = c & 15;
        H8 u;
        const float* src = word_vec + (size_t)(vbase + r) * NW + cc * 8;
        if (cc < 12) {
            const float4 x0 = *reinterpret_cast<const float4*>(src);
            const float4 x1 = *reinterpret_cast<const float4*>(src + 4);
            u.e[0] = (_Float16)x0.x; u.e[1] = (_Float16)x0.y;
            u.e[2] = (_Float16)x0.z; u.e[3] = (_Float16)x0.w;
            u.e[4] = (_Float16)x1.x; u.e[5] = (_Float16)x1.y;
            u.e[6] = (_Float16)x1.z; u.e[7] = (_Float16)x1.w;
        } else {
#pragma unroll
            for (int j = 0; j < 8; ++j) {
                const int k = cc * 8 + j;
                u.e[j] = (k < NW) ? (_Float16)word_vec[(size_t)(vbase + r) * NW + k]
                                  : (_Float16)0.f;
            }
        }
        *reinterpret_cast<v8h*>(&wt[r * 128 + ((cc ^ (r & 7)) << 3)]) = u.v;
    }
    // ---- stage eff: 112 rows x 16 chunks ----
    for (int c = tid; c < 112 * 16; c += 256) {
        const int f = c >> 4, cc = c & 15;
        H8 u;
        if (f < N1 && cc < 12) {
            const float4 a0 = *reinterpret_cast<const float4*>(&W1[f * 200 + cc * 8]);
            const float4 a1 = *reinterpret_cast<const float4*>(&W1[f * 200 + cc * 8 + 4]);
            const float4 b0 = *reinterpret_cast<const float4*>(&W1[f * 200 + 100 + cc * 8]);
            const float4 b1 = *reinterpret_cast<const float4*>(&W1[f * 200 + 104 + cc * 8]);
            u.e[0] = (_Float16)(a0.x + b0.x); u.e[1] = (_Float16)(a0.y + b0.y);
            u.e[2] = (_Float16)(a0.z + b0.z); u.e[3] = (_Float16)(a0.w + b0.w);
            u.e[4] = (_Float16)(a1.x + b1.x); u.e[5] = (_Float16)(a1.y + b1.y);
            u.e[6] = (_Float16)(a1.z + b1.z); u.e[7] = (_Float16)(a1.w + b1.w);
        } else {
#pragma unroll
            for (int j = 0; j < 8; ++j) {
                const int k = cc * 8 + j;
                u.e[j] = (f < N1 && k < NW)
                    ? (_Float16)(W1[f * 200 + k] + W1[f * 200 + 100 + k])
                    : (_Float16)0.f;
            }
        }
        *reinterpret_cast<v8h*>(&eff[f * 128 + ((cc ^ (f & 7)) << 3)]) = u.v;
    }
    __syncthreads();

    const int lane = tid & 63;
    const int wave = tid >> 6;
    const int rbase = wave * 16;
    const int mr = lane & 15;
    const int kg = lane >> 4;

    v8h a[4];
#pragma unroll
    for (int s = 0; s < 4; ++s) {
        const int k = s * 32 + kg * 8;
        a[s] = *reinterpret_cast<const v8h*>(
            &wt[(rbase + mr) * 128 + (k ^ ((mr & 7) << 3))]);
    }

#pragma unroll
    for (int t = 0; t < 7; ++t) {
        v4f acc = {0.f, 0.f, 0.f, 0.f};
        const int f = t * 16 + mr;
#pragma unroll
        for (int s = 0; s < 4; ++s) {
            const int k = s * 32 + kg * 8;
            const v8h b = *reinterpret_cast<const v8h*>(
                &eff[f * 128 + (k ^ ((f & 7) << 3))]);
            acc = __builtin_amdgcn_mfma_f32_16x16x32_f16(a[s], b, acc, 0, 0, 0);
        }
        if (f < N1) {
            const size_t vrow = (size_t)(vbase + rbase + kg * 4);
#pragma unroll
            for (int j = 0; j < 4; ++j)
                S8[(vrow + j) * SROWB + f] = enc_fp8(acc[j]);
        }
    }
}

// ---------------------------------------------------------------------------
// k_gather: one block (256 thr = 4 waves) per batch row. Waves split 86
// windows {22,22,22,20}; running max starts at 0 (relu(max)==max(0,..));
// windows processed in PAIRS for 8 loads in flight. Output hsum/86 as fp16,
// PRE-SWIZZLED for k_mm's A-tile (row = b & 63).
// ---------------------------------------------------------------------------
__global__ __launch_bounds__(256) void k_gather(const int* __restrict__ ent_words,
                                                const unsigned char* __restrict__ S8,
                                                _Float16* __restrict__ hsum_h) {
    __shared__ __align__(16) int woff[344];
    __shared__ __align__(16) float part[4][N1];

    const int b    = blockIdx.x;
    const int tid  = threadIdx.x;
    const int lane = tid & 63;
    const int wave = tid >> 6;

    for (int l = tid; l < LL; l += 256)
        woff[l] = ent_words[b * LL + l] << 7;     // byte offset (128-B rows)
    __syncthreads();

    const char* Sc = reinterpret_cast<const char*>(S8);
    const uint32_t laneoff = (uint32_t)lane * 2u;

    if (lane < 50) {
        float acc0 = 0.f, acc1 = 0.f;
        const int pbeg = wave * 22;
        const int pfull_end = (wave == 3) ? 85 : pbeg + 22;   // full windows only
        int p = pbeg;
        for (; p + 1 < pfull_end; p += 2) {
            const int4 wa = *reinterpret_cast<const int4*>(&woff[p * 4]);
            const int4 wb = *reinterpret_cast<const int4*>(&woff[p * 4 + 4]);
            // issue all 8 loads before consuming
            const unsigned short sa0 = *reinterpret_cast<const unsigned short*>(Sc + ((uint32_t)wa.x + laneoff));
            const unsigned short sa1 = *reinterpret_cast<const unsigned short*>(Sc + ((uint32_t)wa.y + laneoff));
            const unsigned short sa2 = *reinterpret_cast<const unsigned short*>(Sc + ((uint32_t)wa.z + laneoff));
            const unsigned short sa3 = *reinterpret_cast<const unsigned short*>(Sc + ((uint32_t)wa.w + laneoff));
            const unsigned short sb0 = *reinterpret_cast<const unsigned short*>(Sc + ((uint32_t)wb.x + laneoff));
            const unsigned short sb1 = *reinterpret_cast<const unsigned short*>(Sc + ((uint32_t)wb.y + laneoff));
            const unsigned short sb2 = *reinterpret_cast<const unsigned short*>(Sc + ((uint32_t)wb.z + laneoff));
            const unsigned short sb3 = *reinterpret_cast<const unsigned short*>(Sc + ((uint32_t)wb.w + laneoff));
            const v2f ra0 = dec2_fp8(sa0), ra1 = dec2_fp8(sa1), ra2 = dec2_fp8(sa2), ra3 = dec2_fp8(sa3);
            const v2f rb0 = dec2_fp8(sb0), rb1 = dec2_fp8(sb1), rb2 = dec2_fp8(sb2), rb3 = dec2_fp8(sb3);
            acc0 += fmaxf(fmaxf(fmaxf(ra0.x, ra1.x), fmaxf(ra2.x, ra3.x)), 0.f)
                  + fmaxf(fmaxf(fmaxf(rb0.x, rb1.x), fmaxf(rb2.x, rb3.x)), 0.f);
            acc1 += fmaxf(fmaxf(fmaxf(ra0.y, ra1.y), fmaxf(ra2.y, ra3.y)), 0.f)
                  + fmaxf(fmaxf(fmaxf(rb0.y, rb1.y), fmaxf(rb2.y, rb3.y)), 0.f);
        }
        if (p < pfull_end) {   // odd leftover full window (wave 3: p=84)
            const int4 wa = *reinterpret_cast<const int4*>(&woff[p * 4]);
            const unsigned short s0 = *reinterpret_cast<const unsigned short*>(Sc + ((uint32_t)wa.x + laneoff));
            const unsigned short s1 = *reinterpret_cast<const unsigned short*>(Sc + ((uint32_t)wa.y + laneoff));
            const unsigned short s2 = *reinterpret_cast<const unsigned short*>(Sc + ((uint32_t)wa.z + laneoff));
            const unsigned short s3 = *reinterpret_cast<const unsigned short*>(Sc + ((uint32_t)wa.w + laneoff));
            const v2f r0 = dec2_fp8(s0), r1 = dec2_fp8(s1), r2 = dec2_fp8(s2), r3 = dec2_fp8(s3);
            acc0 += fmaxf(fmaxf(fmaxf(r0.x, r1.x), fmaxf(r2.x, r3.x)), 0.f);
            acc1 += fmaxf(fmaxf(fmaxf(r0.y, r1.y), fmaxf(r2.y, r3.y)), 0.f);
        }
        if (wave == 3) {       // tail window 85: tokens 340..342
            const unsigned short s0 = *reinterpret_cast<const unsigned short*>(Sc + ((uint32_t)woff[340] + laneoff));
            const unsigned short s1 = *reinterpret_cast<const unsigned short*>(Sc + ((uint32_t)woff[341] + laneoff));
            const unsigned short s2 = *reinterpret_cast<const unsigned short*>(Sc + ((uint32_t)woff[342] + laneoff));
            const v2f r0 = dec2_fp8(s0), r1 = dec2_fp8(s1), r2 = dec2_fp8(s2);
            acc0 += fmaxf(fmaxf(fmaxf(r0.x, r1.x), r2.x), 0.f);
            acc1 += fmaxf(fmaxf(fmaxf(r0.y, r1.y), r2.y), 0.f);
        }
        part[wave][2 * lane]     = acc0;
        part[wave][2 * lane + 1] = acc1;
    }
    __syncthreads();

    // combine, scale by 1/86, quantize fp16, store pre-swizzled chunk
    if (tid < 16) {
        const int cc = tid;
        H8 u;
#pragma unroll
        for (int j = 0; j < 8; ++j) {
            const int f = cc * 8 + j;
            float v = 0.f;
            if (f < N1)
                v = (part[0][f] + part[1][f] + part[2][f] + part[3][f]) * (1.0f / (float)PP);
            u.e[j] = (_Float16)v;
        }
        *reinterpret_cast<v8h*>(&hsum_h[(size_t)b * 128 + ((cc ^ (b & 7)) << 3)]) = u.v;
    }
}

// ---------------------------------------------------------------------------
// k_mm: out[4096,100] = hsum[4096,100(f)] @ W2[n][f]  (B needs no transpose:
// B-frag rows are output cols n, k-dim is f). A-tile is a raw 16 KB copy
// (k_gather pre-swizzled). Same MFMA template as k_table. 64 blocks.
// ---------------------------------------------------------------------------
__global__ __launch_bounds__(256) void k_mm(const _Float16* __restrict__ hsum_h,
                                            const float* __restrict__ W2,
                                            float* __restrict__ out) {
    const int tid = threadIdx.x;
    __shared__ _Float16 wt[64 * 128];    // A tile (already swizzled), 16 KB
    __shared__ _Float16 wf[112 * 128];   // W2 as [n][f], swizzled, 28 KB
    const int vbase = blockIdx.x * 64;

    {   // raw copy A tile: 1024 x 16 B
        const uint4* src = reinterpret_cast<const uint4*>(hsum_h + (size_t)vbase * 128);
        uint4* dst = reinterpret_cast<uint4*>(wt);
#pragma unroll
        for (int i = 0; i < 4; ++i)
            dst[tid + i * 256] = src[tid + i * 256];
    }
    for (int c = tid; c < 112 * 16; c += 256) {
        const int n = c >> 4, cc = c & 15;
        H8 u;
        if (n < N2 && cc < 12) {
            const float4 a0 = *reinterpret_cast<const float4*>(&W2[n * N1 + cc * 8]);
            const float4 a1 = *reinterpret_cast<const float4*>(&W2[n * N1 + cc * 8 + 4]);
            u.e[0] = (_Float16)a0.x; u.e[1] = (_Float16)a0.y;
            u.e[2] = (_Float16)a0.z; u.e[3] = (_Float16)a0.w;
            u.e[4] = (_Float16)a1.x; u.e[5] = (_Float16)a1.y;
            u.e[6] = (_Float16)a1.z; u.e[7] = (_Float16)a1.w;
        } else {
#pragma unroll
            for (int j = 0; j < 8; ++j) {
                const int f = cc * 8 + j;
                u.e[j] = (n < N2 && f < N1) ? (_Float16)W2[n * N1 + f] : (_Float16)0.f;
            }
        }
        *reinterpret_cast<v8h*>(&wf[n * 128 + ((cc ^ (n & 7)) << 3)]) = u.v;
    }
    __syncthreads();

    const int lane = tid & 63;
    const int wave = tid >> 6;
    const int rbase = wave * 16;
    const int mr = lane & 15;
    const int kg = lane >> 4;

    v8h a[4];
#pragma unroll
    for (int s = 0; s < 4; ++s) {
        const int k = s * 32 + kg * 8;
        a[s] = *reinterpret_cast<const v8h*>(
            &wt[(rbase + mr) * 128 + (k ^ ((mr & 7) << 3))]);
    }

#pragma unroll
    for (int t = 0; t < 7; ++t) {
        v4f acc = {0.f, 0.f, 0.f, 0.f};
        const int n = t * 16 + mr;
#pragma unroll
        for (int s = 0; s < 4; ++s) {
            const int k = s * 32 + kg * 8;
            const v8h bf = *reinterpret_cast<const v8h*>(
                &wf[n * 128 + (k ^ ((n & 7) << 3))]);
            acc = __builtin_amdgcn_mfma_f32_16x16x32_f16(a[s], bf, acc, 0, 0, 0);
        }
        if (n < N2) {
            const int row = vbase + rbase + kg * 4;
#pragma unroll
            for (int j = 0; j < 4; ++j)
                out[(size_t)(row + j) * N2 + n] = acc[j];
        }
    }
}

// ---------------------------------------------------------------------------
extern "C" void kernel_launch(void* const* d_in, const int* in_sizes, int n_in,
                              void* d_out, int out_size, void* d_ws, size_t ws_size,
                              hipStream_t stream) {
    const int*   ent_words = (const int*)d_in[0];
    const float* word_vec  = (const float*)d_in[1];
    const float* W1        = (const float*)d_in[2];
    const float* W2        = (const float*)d_in[3];
    float* out = (float*)d_out;

    unsigned char* S8     = (unsigned char*)d_ws;                    // 5.12 MB
    _Float16*      hsum_h = (_Float16*)((char*)d_ws + (size_t)VOCAB * SROWB);  // 1 MB

    k_table<<<625, 256, 0, stream>>>(word_vec, W1, S8);
    k_gather<<<BB, 256, 0, stream>>>(ent_words, S8, hsum_h);
    k_mm<<<64, 256, 0, stream>>>(hsum_h, W2, out);
}

// Round 7
// 47.486 us; speedup vs baseline: 1.0922x; 1.0922x over previous
//
#include <hip/hip_runtime.h>
#include <hip/hip_fp16.h>
#include <hip/hip_fp8.h>
#include <stdint.h>

#define VOCAB 40000
#define NW    100
#define N1    100
#define N2    100
#define BB    4096
#define LL    343
#define PP    86      // pooling length: (343-1)/4 + 1
#define SROWB 128     // S row stride in BYTES (one 128-B cache line, fp8)

typedef _Float16 v8h __attribute__((ext_vector_type(8)));
typedef float    v4f __attribute__((ext_vector_type(4)));
typedef float    v2f __attribute__((ext_vector_type(2)));

union H8 { v8h v; _Float16 e[8]; };

__device__ __forceinline__ unsigned char enc_fp8(float v) {
#if __has_builtin(__builtin_amdgcn_cvt_pk_fp8_f32)
    int pk = __builtin_amdgcn_cvt_pk_fp8_f32(v, v, 0, false);
    return (unsigned char)(pk & 0xff);
#else
    __hip_fp8_e4m3 h(v);
    return h.__x;
#endif
}

__device__ __forceinline__ v2f dec2_fp8(unsigned int us) {
#if __has_builtin(__builtin_amdgcn_cvt_pk_f32_fp8)
    return __builtin_amdgcn_cvt_pk_f32_fp8((int)us, false);
#else
    __hip_fp8_e4m3 a, b;
    a.__x = (unsigned char)(us & 0xff);
    b.__x = (unsigned char)((us >> 8) & 0xff);
    v2f r; r.x = (float)a; r.y = (float)b; return r;
#endif
}

// ---------------------------------------------------------------------------
// k_table: blocks 0..624 compute S[v][f] = sum_k wv[v][k]*(W1[f][k]+W1[f][100+k])
// via mfma_f32_16x16x32_f16 (fp16 inputs, fp32 accum), output quantized to
// fp8 e4m3 rows of 128 B. 64 vocab rows/block, 4 waves, 7 col-tiles x 4 k-steps.
// LDS XOR-swizzled for conflict-free ds_read_b128. Block 625: W2 transpose.
// ---------------------------------------------------------------------------
__global__ __launch_bounds__(256) void k_table(const float* __restrict__ word_vec,
                                               const float* __restrict__ W1,
                                               const float* __restrict__ W2,
                                               unsigned char* __restrict__ S8,
                                               float* __restrict__ W2T) {
    const int tid = threadIdx.x;

    if (blockIdx.x == 625) {            // W2T[f][n] = W2[n][f]
        for (int idx = tid; idx < N1 * N2; idx += 256) {
            int f = idx / N2;
            int n = idx - f * N2;
            W2T[idx] = W2[n * N1 + f];
        }
        return;
    }

    __shared__ _Float16 wt[64 * 128];    // word tile, swizzled   (16 KB)
    __shared__ _Float16 eff[112 * 128];  // eff filters, swizzled (28 KB)
    const int vbase = blockIdx.x * 64;

    // ---- stage word tile: 64 rows x 16 chunks of 8 halfs ----
    for (int c = tid; c < 64 * 16; c += 256) {
        const int r = c >> 4, cc = c & 15;
        H8 u;
        const float* src = word_vec + (size_t)(vbase + r) * NW + cc * 8;
        if (cc < 12) {
            const float4 x0 = *reinterpret_cast<const float4*>(src);
            const float4 x1 = *reinterpret_cast<const float4*>(src + 4);
            u.e[0] = (_Float16)x0.x; u.e[1] = (_Float16)x0.y;
            u.e[2] = (_Float16)x0.z; u.e[3] = (_Float16)x0.w;
            u.e[4] = (_Float16)x1.x; u.e[5] = (_Float16)x1.y;
            u.e[6] = (_Float16)x1.z; u.e[7] = (_Float16)x1.w;
        } else {
#pragma unroll
            for (int j = 0; j < 8; ++j) {
                const int k = cc * 8 + j;
                u.e[j] = (k < NW) ? (_Float16)word_vec[(size_t)(vbase + r) * NW + k]
                                  : (_Float16)0.f;
            }
        }
        *reinterpret_cast<v8h*>(&wt[r * 128 + ((cc ^ (r & 7)) << 3)]) = u.v;
    }
    // ---- stage eff: 112 rows x 16 chunks ----
    for (int c = tid; c < 112 * 16; c += 256) {
        const int f = c >> 4, cc = c & 15;
        H8 u;
        if (f < N1 && cc < 12) {
            const float4 a0 = *reinterpret_cast<const float4*>(&W1[f * 200 + cc * 8]);
            const float4 a1 = *reinterpret_cast<const float4*>(&W1[f * 200 + cc * 8 + 4]);
            const float4 b0 = *reinterpret_cast<const float4*>(&W1[f * 200 + 100 + cc * 8]);
            const float4 b1 = *reinterpret_cast<const float4*>(&W1[f * 200 + 104 + cc * 8]);
            u.e[0] = (_Float16)(a0.x + b0.x); u.e[1] = (_Float16)(a0.y + b0.y);
            u.e[2] = (_Float16)(a0.z + b0.z); u.e[3] = (_Float16)(a0.w + b0.w);
            u.e[4] = (_Float16)(a1.x + b1.x); u.e[5] = (_Float16)(a1.y + b1.y);
            u.e[6] = (_Float16)(a1.z + b1.z); u.e[7] = (_Float16)(a1.w + b1.w);
        } else {
#pragma unroll
            for (int j = 0; j < 8; ++j) {
                const int k = cc * 8 + j;
                u.e[j] = (f < N1 && k < NW)
                    ? (_Float16)(W1[f * 200 + k] + W1[f * 200 + 100 + k])
                    : (_Float16)0.f;
            }
        }
        *reinterpret_cast<v8h*>(&eff[f * 128 + ((cc ^ (f & 7)) << 3)]) = u.v;
    }
    __syncthreads();

    const int lane = tid & 63;
    const int wave = tid >> 6;
    const int rbase = wave * 16;
    const int mr = lane & 15;
    const int kg = lane >> 4;

    v8h a[4];
#pragma unroll
    for (int s = 0; s < 4; ++s) {
        const int k = s * 32 + kg * 8;
        a[s] = *reinterpret_cast<const v8h*>(
            &wt[(rbase + mr) * 128 + (k ^ ((mr & 7) << 3))]);
    }

#pragma unroll
    for (int t = 0; t < 7; ++t) {
        v4f acc = {0.f, 0.f, 0.f, 0.f};
        const int f = t * 16 + mr;
#pragma unroll
        for (int s = 0; s < 4; ++s) {
            const int k = s * 32 + kg * 8;
            const v8h b = *reinterpret_cast<const v8h*>(
                &eff[f * 128 + (k ^ ((f & 7) << 3))]);
            acc = __builtin_amdgcn_mfma_f32_16x16x32_f16(a[s], b, acc, 0, 0, 0);
        }
        if (f < N1) {
            const size_t vrow = (size_t)(vbase + rbase + kg * 4);
#pragma unroll
            for (int j = 0; j < 4; ++j)
                S8[(vrow + j) * SROWB + f] = enc_fp8(acc[j]);
        }
    }
}

// ---------------------------------------------------------------------------
// k_main: one block (256 thr = 4 waves) per batch row. Waves split the 86
// windows {22,22,22,20+tail}. Gather runs 4 windows (16 loads) in flight.
// Epilogue in-kernel (R6 showed splitting it out costs ~4 us).
// ---------------------------------------------------------------------------
__global__ __launch_bounds__(256) void k_main(const int* __restrict__ ent_words,
                                              const unsigned char* __restrict__ S8,
                                              const float* __restrict__ W2T,
                                              float* __restrict__ out) {
    __shared__ __align__(16) int woff[344];
    __shared__ __align__(16) float part[4][N1];
    __shared__ __align__(16) float hsum[N1];

    const int b    = blockIdx.x;
    const int tid  = threadIdx.x;
    const int lane = tid & 63;
    const int wave = tid >> 6;

    for (int l = tid; l < LL; l += 256)
        woff[l] = ent_words[b * LL + l] << 7;     // byte offset (128-B rows)
    __syncthreads();

    const char* Sc = reinterpret_cast<const char*>(S8);
    const uint32_t laneoff = (uint32_t)lane * 2u;

    if (lane < 50) {
        float acc0 = 0.f, acc1 = 0.f;
        const int pbeg = wave * 22;
        const int pfull_end = (wave == 3) ? 85 : pbeg + 22;   // full windows only
        int p = pbeg;
        // ---- 4 windows per iteration: 16 loads in flight ----
        for (; p + 3 < pfull_end; p += 4) {
            const int4 wa = *reinterpret_cast<const int4*>(&woff[p * 4]);
            const int4 wb = *reinterpret_cast<const int4*>(&woff[p * 4 + 4]);
            const int4 wc = *reinterpret_cast<const int4*>(&woff[p * 4 + 8]);
            const int4 wd = *reinterpret_cast<const int4*>(&woff[p * 4 + 12]);
            const unsigned short sa0 = *reinterpret_cast<const unsigned short*>(Sc + ((uint32_t)wa.x + laneoff));
            const unsigned short sa1 = *reinterpret_cast<const unsigned short*>(Sc + ((uint32_t)wa.y + laneoff));
            const unsigned short sa2 = *reinterpret_cast<const unsigned short*>(Sc + ((uint32_t)wa.z + laneoff));
            const unsigned short sa3 = *reinterpret_cast<const unsigned short*>(Sc + ((uint32_t)wa.w + laneoff));
            const unsigned short sb0 = *reinterpret_cast<const unsigned short*>(Sc + ((uint32_t)wb.x + laneoff));
            const unsigned short sb1 = *reinterpret_cast<const unsigned short*>(Sc + ((uint32_t)wb.y + laneoff));
            const unsigned short sb2 = *reinterpret_cast<const unsigned short*>(Sc + ((uint32_t)wb.z + laneoff));
            const unsigned short sb3 = *reinterpret_cast<const unsigned short*>(Sc + ((uint32_t)wb.w + laneoff));
            const unsigned short sc0 = *reinterpret_cast<const unsigned short*>(Sc + ((uint32_t)wc.x + laneoff));
            const unsigned short sc1 = *reinterpret_cast<const unsigned short*>(Sc + ((uint32_t)wc.y + laneoff));
            const unsigned short sc2 = *reinterpret_cast<const unsigned short*>(Sc + ((uint32_t)wc.z + laneoff));
            const unsigned short sc3 = *reinterpret_cast<const unsigned short*>(Sc + ((uint32_t)wc.w + laneoff));
            const unsigned short sd0 = *reinterpret_cast<const unsigned short*>(Sc + ((uint32_t)wd.x + laneoff));
            const unsigned short sd1 = *reinterpret_cast<const unsigned short*>(Sc + ((uint32_t)wd.y + laneoff));
            const unsigned short sd2 = *reinterpret_cast<const unsigned short*>(Sc + ((uint32_t)wd.z + laneoff));
            const unsigned short sd3 = *reinterpret_cast<const unsigned short*>(Sc + ((uint32_t)wd.w + laneoff));
            const v2f ra0 = dec2_fp8(sa0), ra1 = dec2_fp8(sa1), ra2 = dec2_fp8(sa2), ra3 = dec2_fp8(sa3);
            const v2f rb0 = dec2_fp8(sb0), rb1 = dec2_fp8(sb1), rb2 = dec2_fp8(sb2), rb3 = dec2_fp8(sb3);
            const v2f rc0 = dec2_fp8(sc0), rc1 = dec2_fp8(sc1), rc2 = dec2_fp8(sc2), rc3 = dec2_fp8(sc3);
            const v2f rd0 = dec2_fp8(sd0), rd1 = dec2_fp8(sd1), rd2 = dec2_fp8(sd2), rd3 = dec2_fp8(sd3);
            acc0 += fmaxf(fmaxf(fmaxf(ra0.x, ra1.x), fmaxf(ra2.x, ra3.x)), 0.f)
                  + fmaxf(fmaxf(fmaxf(rb0.x, rb1.x), fmaxf(rb2.x, rb3.x)), 0.f)
                  + fmaxf(fmaxf(fmaxf(rc0.x, rc1.x), fmaxf(rc2.x, rc3.x)), 0.f)
                  + fmaxf(fmaxf(fmaxf(rd0.x, rd1.x), fmaxf(rd2.x, rd3.x)), 0.f);
            acc1 += fmaxf(fmaxf(fmaxf(ra0.y, ra1.y), fmaxf(ra2.y, ra3.y)), 0.f)
                  + fmaxf(fmaxf(fmaxf(rb0.y, rb1.y), fmaxf(rb2.y, rb3.y)), 0.f)
                  + fmaxf(fmaxf(fmaxf(rc0.y, rc1.y), fmaxf(rc2.y, rc3.y)), 0.f)
                  + fmaxf(fmaxf(fmaxf(rd0.y, rd1.y), fmaxf(rd2.y, rd3.y)), 0.f);
        }
        // ---- pair remainder ----
        for (; p + 1 < pfull_end; p += 2) {
            const int4 wa = *reinterpret_cast<const int4*>(&woff[p * 4]);
            const int4 wb = *reinterpret_cast<const int4*>(&woff[p * 4 + 4]);
            const unsigned short sa0 = *reinterpret_cast<const unsigned short*>(Sc + ((uint32_t)wa.x + laneoff));
            const unsigned short sa1 = *reinterpret_cast<const unsigned short*>(Sc + ((uint32_t)wa.y + laneoff));
            const unsigned short sa2 = *reinterpret_cast<const unsigned short*>(Sc + ((uint32_t)wa.z + laneoff));
            const unsigned short sa3 = *reinterpret_cast<const unsigned short*>(Sc + ((uint32_t)wa.w + laneoff));
            const unsigned short sb0 = *reinterpret_cast<const unsigned short*>(Sc + ((uint32_t)wb.x + laneoff));
            const unsigned short sb1 = *reinterpret_cast<const unsigned short*>(Sc + ((uint32_t)wb.y + laneoff));
            const unsigned short sb2 = *reinterpret_cast<const unsigned short*>(Sc + ((uint32_t)wb.z + laneoff));
            const unsigned short sb3 = *reinterpret_cast<const unsigned short*>(Sc + ((uint32_t)wb.w + laneoff));
            const v2f ra0 = dec2_fp8(sa0), ra1 = dec2_fp8(sa1), ra2 = dec2_fp8(sa2), ra3 = dec2_fp8(sa3);
            const v2f rb0 = dec2_fp8(sb0), rb1 = dec2_fp8(sb1), rb2 = dec2_fp8(sb2), rb3 = dec2_fp8(sb3);
            acc0 += fmaxf(fmaxf(fmaxf(ra0.x, ra1.x), fmaxf(ra2.x, ra3.x)), 0.f)
                  + fmaxf(fmaxf(fmaxf(rb0.x, rb1.x), fmaxf(rb2.x, rb3.x)), 0.f);
            acc1 += fmaxf(fmaxf(fmaxf(ra0.y, ra1.y), fmaxf(ra2.y, ra3.y)), 0.f)
                  + fmaxf(fmaxf(fmaxf(rb0.y, rb1.y), fmaxf(rb2.y, rb3.y)), 0.f);
        }
        if (p < pfull_end) {   // single leftover full window
            const int4 wa = *reinterpret_cast<const int4*>(&woff[p * 4]);
            const unsigned short s0 = *reinterpret_cast<const unsigned short*>(Sc + ((uint32_t)wa.x + laneoff));
            const unsigned short s1 = *reinterpret_cast<const unsigned short*>(Sc + ((uint32_t)wa.y + laneoff));
            const unsigned short s2 = *reinterpret_cast<const unsigned short*>(Sc + ((uint32_t)wa.z + laneoff));
            const unsigned short s3 = *reinterpret_cast<const unsigned short*>(Sc + ((uint32_t)wa.w + laneoff));
            const v2f r0 = dec2_fp8(s0), r1 = dec2_fp8(s1), r2 = dec2_fp8(s2), r3 = dec2_fp8(s3);
            acc0 += fmaxf(fmaxf(fmaxf(r0.x, r1.x), fmaxf(r2.x, r3.x)), 0.f);
            acc1 += fmaxf(fmaxf(fmaxf(r0.y, r1.y), fmaxf(r2.y, r3.y)), 0.f);
        }
        if (wave == 3) {       // tail window 85: tokens 340..342
            const unsigned short s0 = *reinterpret_cast<const unsigned short*>(Sc + ((uint32_t)woff[340] + laneoff));
            const unsigned short s1 = *reinterpret_cast<const unsigned short*>(Sc + ((uint32_t)woff[341] + laneoff));
            const unsigned short s2 = *reinterpret_cast<const unsigned short*>(Sc + ((uint32_t)woff[342] + laneoff));
            const v2f r0 = dec2_fp8(s0), r1 = dec2_fp8(s1), r2 = dec2_fp8(s2);
            acc0 += fmaxf(fmaxf(fmaxf(r0.x, r1.x), r2.x), 0.f);
            acc1 += fmaxf(fmaxf(fmaxf(r0.y, r1.y), r2.y), 0.f);
        }
        part[wave][2 * lane]     = acc0;
        part[wave][2 * lane + 1] = acc1;
    }
    __syncthreads();

    if (tid < N1) {
        hsum[tid] = part[0][tid] + part[1][tid] + part[2][tid] + part[3][tid];
    }
    __syncthreads();

    if (tid < N2) {
        const int n = tid;
        float o = 0.f;
#pragma unroll 4
        for (int f = 0; f < N1; ++f) {
            o += hsum[f] * W2T[f * N2 + n];             // coalesced across threads
        }
        out[b * N2 + n] = o * (1.0f / (float)PP);
    }
}

// ---------------------------------------------------------------------------
extern "C" void kernel_launch(void* const* d_in, const int* in_sizes, int n_in,
                              void* d_out, int out_size, void* d_ws, size_t ws_size,
                              hipStream_t stream) {
    const int*   ent_words = (const int*)d_in[0];
    const float* word_vec  = (const float*)d_in[1];
    const float* W1        = (const float*)d_in[2];
    const float* W2        = (const float*)d_in[3];
    float* out = (float*)d_out;

    unsigned char* S8  = (unsigned char*)d_ws;                          // 5.12 MB
    float*         W2T = (float*)((char*)d_ws + (size_t)VOCAB * SROWB);

    k_table<<<626, 256, 0, stream>>>(word_vec, W1, W2, S8, W2T);
    k_main<<<BB, 256, 0, stream>>>(ent_words, S8, W2T, out);
}